// Round 8
// baseline (883.977 us; speedup 1.0000x reference)
//
#include <hip/hip_runtime.h>
#include <hip/hip_bf16.h>
#include <math.h>

typedef __attribute__((ext_vector_type(8))) short s16x8;
typedef __attribute__((ext_vector_type(4))) float f32x4;

#define T_TOK 16384
#define D_DIM 1024
#define F_DIM 2048
#define E_NUM 8
#define RCAP 34816   // 2*T + 8*256 worst-case 256-padded rows
#define MAXT2 272    // 128-row tiles

__device__ __forceinline__ unsigned short f2b(float f) {
  unsigned u = __float_as_uint(f);
  u += 0x7fff + ((u >> 16) & 1);
  return (unsigned short)(u >> 16);
}
__device__ __forceinline__ unsigned pk2(float a, float b) {
  __hip_bfloat162 h = __float22bfloat162_rn(make_float2(a, b));
  return *reinterpret_cast<unsigned*>(&h);
}

// ---------------- weight cast fp32 -> bf16 ----------------
__global__ void castw_k(const float* __restrict__ w1, const float* __restrict__ w2,
                        unsigned short* __restrict__ w1b, unsigned short* __restrict__ w2b) {
  size_t i = ((size_t)blockIdx.x * 256 + threadIdx.x) * 4;
  float4 a = *(const float4*)(w1 + i);
  float4 b = *(const float4*)(w2 + i);
  uint2 ua, ub;
  ua.x = pk2(a.x, a.y); ua.y = pk2(a.z, a.w);
  ub.x = pk2(b.x, b.y); ub.y = pk2(b.z, b.w);
  *(uint2*)(w1b + i) = ua;
  *(uint2*)(w2b + i) = ub;
}

// ---------------- router (+ fused x->bf16 cast) ----------------
__global__ void router_k(const float* __restrict__ x, const float* __restrict__ wr,
                         int* __restrict__ topi, float* __restrict__ topw,
                         float* __restrict__ probs8, unsigned short* __restrict__ xb) {
  int tid = threadIdx.x, wid = tid >> 6, lane = tid & 63;
  int t = blockIdx.x * 4 + wid;
  const float* xr = x + (size_t)t * D_DIM;
  float4 xv[4];
#pragma unroll
  for (int i = 0; i < 4; ++i) xv[i] = *(const float4*)(xr + i * 256 + lane * 4);
#pragma unroll
  for (int i = 0; i < 4; ++i) {
    uint2 u; u.x = pk2(xv[i].x, xv[i].y); u.y = pk2(xv[i].z, xv[i].w);
    *(uint2*)(xb + (size_t)t * D_DIM + i * 256 + lane * 4) = u;
  }
  float logit[E_NUM];
#pragma unroll
  for (int e = 0; e < E_NUM; ++e) {
    const float* wrow = wr + e * D_DIM;
    float p = 0.f;
#pragma unroll
    for (int i = 0; i < 4; ++i) {
      float4 wv = *(const float4*)(wrow + i * 256 + lane * 4);
      p += xv[i].x * wv.x + xv[i].y * wv.y + xv[i].z * wv.z + xv[i].w * wv.w;
    }
    for (int s = 32; s; s >>= 1) p += __shfl_xor(p, s);
    logit[e] = p;
  }
  if (lane == 0) {
    float m = logit[0];
    for (int e = 1; e < E_NUM; ++e) m = fmaxf(m, logit[e]);
    float pr[E_NUM];
    float sum = 0.f;
    for (int e = 0; e < E_NUM; ++e) { pr[e] = expf(logit[e] - m); sum += pr[e]; }
    float inv = 1.f / sum;
    for (int e = 0; e < E_NUM; ++e) { pr[e] *= inv; probs8[t * 8 + e] = pr[e]; }
    int i0 = 0;
    for (int e = 1; e < E_NUM; ++e) if (pr[e] > pr[i0]) i0 = e;
    int i1 = (i0 == 0) ? 1 : 0;
    for (int e = 0; e < E_NUM; ++e) if (e != i0 && pr[e] > pr[i1]) i1 = e;
    float wsum = pr[i0] + pr[i1];
    topi[2 * t] = i0;  topi[2 * t + 1] = i1;
    topw[2 * t] = pr[i0] / wsum;  topw[2 * t + 1] = pr[i1] / wsum;
  }
}

// ---------------- histogram ----------------
__global__ void hist_k(const int* __restrict__ topi, const float* __restrict__ probs8,
                       int* __restrict__ cnt, float* __restrict__ usage) {
  __shared__ int sc[E_NUM];
  __shared__ float su[E_NUM];
  int tid = threadIdx.x;
  if (tid < E_NUM) { sc[tid] = 0; su[tid] = 0.f; }
  __syncthreads();
  for (int i = blockIdx.x * 256 + tid; i < 2 * T_TOK; i += 256 * 64)
    atomicAdd(&sc[topi[i]], 1);
  for (int i = blockIdx.x * 256 + tid; i < 8 * T_TOK; i += 256 * 64)
    atomicAdd(&su[i & 7], probs8[i]);
  __syncthreads();
  if (tid < E_NUM) { atomicAdd(&cnt[tid], sc[tid]); atomicAdd(&usage[tid], su[tid]); }
}

// ---------------- offsets (256-padded) + 128-row tile table + aux ----------------
__global__ void scan_k(const int* __restrict__ cnt, int* __restrict__ offs,
                       int* __restrict__ t2_e, int* __restrict__ t2_rb, int* __restrict__ t2cnt,
                       const float* __restrict__ usage, float* __restrict__ aux) {
  if (threadIdx.x == 0 && blockIdx.x == 0) {
    int o = 0, n = 0;
    for (int e = 0; e < E_NUM; ++e) {
      offs[e] = o;
      int pe = (cnt[e] + 255) & ~255;
      for (int r = 0; r < pe; r += 128) { t2_e[n] = e; t2_rb[n] = o + r; ++n; }
      o += pe;
    }
    offs[E_NUM] = o;
    *t2cnt = n;
    float s = 0.f;
    for (int e = 0; e < E_NUM; ++e) { float m = usage[e] * (1.f / T_TOK); s += m * m; }
    *aux = (float)E_NUM * s;
  }
}

// ---------------- assignment: pair -> row ----------------
__global__ void assign_k(const int* __restrict__ topi, const int* __restrict__ offs,
                         int* __restrict__ cur, int* __restrict__ rowpair) {
  int p = blockIdx.x * 256 + threadIdx.x;
  int lane = threadIdx.x & 63;
  int e = topi[p];
  int r = 0;
#pragma unroll
  for (int ee = 0; ee < E_NUM; ++ee) {
    unsigned long long mask = __ballot(e == ee);
    if (e == ee) {
      int leader = __ffsll((unsigned long long)mask) - 1;
      int rank = __popcll(mask & ((1ull << lane) - 1ull));
      int b = 0;
      if (lane == leader) b = atomicAdd(&cur[ee], (int)__popcll(mask));
      b = __shfl(b, leader);
      r = offs[ee] + b + rank;
    }
  }
  rowpair[r] = p;
}

// ====== reg-staged GEMM body: 128x128 tile, BK=32, 4 waves, 16KB LDS ======
// Per step: barrier; ds_write regs(t); barrier; issue loads(t+1); ds_read+MFMA.
// Swizzle: granule ^= (row>>1)&3 on both ds_write and ds_read (<=2-way, free).

#define RGEMM_LOOP(NT)                                                         \
  s16x8 rA0 = *(const s16x8*)pA0, rA1 = *(const s16x8*)pA1;                    \
  s16x8 rB0 = *(const s16x8*)pB0, rB1 = *(const s16x8*)pB1;                    \
  _Pragma("unroll 4")                                                          \
  for (int t = 0; t < NT; ++t) {                                               \
    if (t) __syncthreads();                                                    \
    *(s16x8*)&As[wo0] = rA0; *(s16x8*)&As[wo1] = rA1;                          \
    *(s16x8*)&Bs[wo0] = rB0; *(s16x8*)&Bs[wo1] = rB1;                          \
    __syncthreads();                                                           \
    if (t < NT - 1) {                                                          \
      pA0 += 32; pA1 += 32; pB0 += 32; pB1 += 32;                              \
      rA0 = *(const s16x8*)pA0; rA1 = *(const s16x8*)pA1;                      \
      rB0 = *(const s16x8*)pB0; rB1 = *(const s16x8*)pB1;                      \
    }                                                                          \
    s16x8 bv[4];                                                               \
    _Pragma("unroll") for (int nn = 0; nn < 4; ++nn)                           \
        bv[nn] = *(const s16x8*)&Bs[(wn * 64 + nn * 16 + rl) * 32 + rg];       \
    _Pragma("unroll") for (int mm = 0; mm < 4; ++mm) {                         \
      s16x8 a = *(const s16x8*)&As[(wm * 64 + mm * 16 + rl) * 32 + rg];        \
      __builtin_amdgcn_s_setprio(1);                                           \
      _Pragma("unroll") for (int nn = 0; nn < 4; ++nn)                         \
        acc[mm][nn] = __builtin_amdgcn_mfma_f32_16x16x32_bf16(                 \
            a, bv[nn], acc[mm][nn], 0, 0, 0);                                  \
      __builtin_amdgcn_s_setprio(0);                                          \
    }                                                                          \
  }

// ---------------- GEMM1: hseg = gelu(gather(xb) @ w1[e]^T) ----------------
__global__ __launch_bounds__(256, 4) void gemm1r_k(
    const unsigned short* __restrict__ xb, const unsigned short* __restrict__ w1b,
    const int* __restrict__ t2_e, const int* __restrict__ t2_rb, const int* __restrict__ t2cnt,
    const int* __restrict__ rowpair, const unsigned short* __restrict__ zrow,
    unsigned short* __restrict__ hseg, int segbase, int segrows) {
  int d = blockIdx.x;
  int tile = (d & 7) + 8 * (d >> 7);   // 16 nt-siblings share d&7 -> same XCD
  int nt = (d >> 3) & 15;
  if (tile >= *t2cnt) return;
  int e = t2_e[tile], rowbase = t2_rb[tile];
  if (rowbase < segbase || rowbase >= segbase + segrows) return;

  __shared__ short As[128 * 32];
  __shared__ short Bs[128 * 32];
  int tid = threadIdx.x, wid = tid >> 6, lane = tid & 63;
  int wm = wid >> 1, wn = wid & 1, rl = lane & 15, g4 = lane >> 4;
  int t4 = tid >> 2, gw = tid & 3;
  int sw = (t4 >> 1) & 3;                    // write swizzle (same for row & row+64)
  int wo0 = t4 * 32 + ((gw ^ sw) << 3);
  int wo1 = (64 + t4) * 32 + ((gw ^ sw) << 3);
  int rg = ((g4 ^ ((rl >> 1) & 3)) << 3);    // read swizzle

  int p0 = rowpair[rowbase + t4], p1 = rowpair[rowbase + 64 + t4];
  const unsigned short* pA0 = (p0 >= 0 ? xb + (size_t)(p0 >> 1) * D_DIM : zrow) + gw * 8;
  const unsigned short* pA1 = (p1 >= 0 ? xb + (size_t)(p1 >> 1) * D_DIM : zrow) + gw * 8;
  const unsigned short* pB0 = w1b + ((size_t)e * F_DIM + nt * 128 + t4) * D_DIM + gw * 8;
  const unsigned short* pB1 = pB0 + (size_t)64 * D_DIM;

  f32x4 acc[4][4] = {};
  RGEMM_LOOP(32)

  size_t rloc = (size_t)(rowbase - segbase);
#pragma unroll
  for (int mm = 0; mm < 4; ++mm)
#pragma unroll
    for (int j = 0; j < 4; ++j) {
      size_t rr = (rloc + wm * 64 + mm * 16 + g4 * 4 + j) * F_DIM;
#pragma unroll
      for (int nn = 0; nn < 4; ++nn) {
        float v = acc[mm][nn][j];
        float g = 0.5f * v * (1.f + erff(v * 0.70710678118f));
        hseg[rr + nt * 128 + wn * 64 + nn * 16 + rl] = f2b(g);
      }
    }
}

// ---------------- GEMM2: out[t] += w * (hseg @ w2[e]^T), atomic scatter ----------------
__global__ __launch_bounds__(256, 4) void gemm2r_k(
    const unsigned short* __restrict__ hseg, const unsigned short* __restrict__ w2b,
    const int* __restrict__ t2_e, const int* __restrict__ t2_rb, const int* __restrict__ t2cnt,
    const int* __restrict__ rowpair, const float* __restrict__ topw,
    float* __restrict__ out, int segbase, int segrows) {
  int d = blockIdx.x;
  int tile = (d & 7) + 8 * (d >> 6);   // 8 nt-siblings share d&7 -> same XCD
  int nt = (d >> 3) & 7;
  if (tile >= *t2cnt) return;
  int e = t2_e[tile], rowbase = t2_rb[tile];
  if (rowbase < segbase || rowbase >= segbase + segrows) return;

  __shared__ short As[128 * 32];
  __shared__ short Bs[128 * 32];
  int tid = threadIdx.x, wid = tid >> 6, lane = tid & 63;
  int wm = wid >> 1, wn = wid & 1, rl = lane & 15, g4 = lane >> 4;
  int t4 = tid >> 2, gw = tid & 3;
  int sw = (t4 >> 1) & 3;
  int wo0 = t4 * 32 + ((gw ^ sw) << 3);
  int wo1 = (64 + t4) * 32 + ((gw ^ sw) << 3);
  int rg = ((g4 ^ ((rl >> 1) & 3)) << 3);

  size_t rloc = (size_t)(rowbase - segbase);
  const unsigned short* pA0 = hseg + (rloc + t4) * F_DIM + gw * 8;
  const unsigned short* pA1 = pA0 + (size_t)64 * F_DIM;
  const unsigned short* pB0 = w2b + ((size_t)e * D_DIM + nt * 128 + t4) * F_DIM + gw * 8;
  const unsigned short* pB1 = pB0 + (size_t)64 * F_DIM;

  f32x4 acc[4][4] = {};
  RGEMM_LOOP(64)

#pragma unroll
  for (int mm = 0; mm < 4; ++mm)
#pragma unroll
    for (int j = 0; j < 4; ++j) {
      int lr = wm * 64 + mm * 16 + g4 * 4 + j;
      int p = rowpair[rowbase + lr];
      if (p >= 0) {
        float wgt = topw[p];
        float* op = out + (size_t)(p >> 1) * D_DIM + nt * 128 + wn * 64 + rl;
#pragma unroll
        for (int nn = 0; nn < 4; ++nn)
          unsafeAtomicAdd(op + nn * 16, wgt * acc[mm][nn][j]);
      }
    }
}

extern "C" void kernel_launch(void* const* d_in, const int* in_sizes, int n_in,
                              void* d_out, int out_size, void* d_ws, size_t ws_size,
                              hipStream_t stream) {
  const float* x  = (const float*)d_in[0];
  const float* wr = (const float*)d_in[1];
  const float* w1 = (const float*)d_in[2];
  const float* w2 = (const float*)d_in[3];
  float* out = (float*)d_out;

  char* ws = (char*)d_ws;
  int* cnt   = (int*)ws;            // [8]
  int* cur   = cnt + 8;             // [8]
  int* offs  = cnt + 16;            // [9]
  int* t2cnt = cnt + 25;            // [1]
  float* usage = (float*)(cnt + 26);  // [8]
  int* t2_e  = cnt + 40;            // [272]
  int* t2_rb = cnt + 312;           // [272]
  unsigned short* zrow = (unsigned short*)(ws + 4096);  // 2KB zeros
  size_t off = 8192;
  int*   topi = (int*)(ws + off);     off += (size_t)2 * T_TOK * 4;
  float* topw = (float*)(ws + off);   off += (size_t)2 * T_TOK * 4;
  int*   rowpair = (int*)(ws + off);  off += (size_t)RCAP * 4;
  float* probs8 = (float*)(ws + off); off += (size_t)T_TOK * 8 * 4;
  off = (off + 255) & ~(size_t)255;

  unsigned short* xb = (unsigned short*)(ws + off);
  off += (size_t)T_TOK * D_DIM * 2;                       // 33.6 MB
  unsigned short* w1b = (unsigned short*)(ws + off);
  off += (size_t)E_NUM * F_DIM * D_DIM * 2;               // 33.6 MB
  unsigned short* w2b = (unsigned short*)(ws + off);
  off += (size_t)E_NUM * F_DIM * D_DIM * 2;               // 33.6 MB
  if (ws_size < off + (size_t)4096 * F_DIM * 2) return;   // need >= 16.8MB hseg
  size_t avail = ws_size - off;
  size_t segcap = (avail / ((size_t)F_DIM * 2)) & ~(size_t)255;
  int segrows = segcap > (size_t)RCAP ? RCAP : (int)segcap;
  unsigned short* hseg = (unsigned short*)(ws + off);
  int nseg = (RCAP + segrows - 1) / segrows;

  hipMemsetAsync(ws, 0, 8192, stream);
  hipMemsetAsync(rowpair, 0xFF, (size_t)RCAP * 4, stream);
  hipMemsetAsync(d_out, 0, (size_t)out_size * 4, stream);
  castw_k<<<16384, 256, 0, stream>>>(w1, w2, w1b, w2b);
  router_k<<<T_TOK / 4, 256, 0, stream>>>(x, wr, topi, topw, probs8, xb);
  hist_k<<<64, 256, 0, stream>>>(topi, probs8, cnt, usage);
  scan_k<<<1, 64, 0, stream>>>(cnt, offs, t2_e, t2_rb, t2cnt, usage, out + (size_t)T_TOK * D_DIM);
  assign_k<<<2 * T_TOK / 256, 256, 0, stream>>>(topi, offs, cur, rowpair);

  for (int s = 0; s < nseg; ++s) {
    int segbase = s * segrows;
    gemm1r_k<<<8 * 16 * 34, 256, 0, stream>>>(xb, w1b, t2_e, t2_rb, t2cnt, rowpair, zrow,
                                              hseg, segbase, segrows);
    gemm2r_k<<<8 * 8 * 34, 256, 0, stream>>>(hseg, w2b, t2_e, t2_rb, t2cnt, rowpair, topw,
                                             out, segbase, segrows);
  }
}

// Round 9
// 571.722 us; speedup vs baseline: 1.5462x; 1.5462x over previous
//
#include <hip/hip_runtime.h>
#include <hip/hip_bf16.h>
#include <math.h>

typedef __attribute__((ext_vector_type(8))) short s16x8;
typedef __attribute__((ext_vector_type(4))) float f32x4;

#define T_TOK 16384
#define D_DIM 1024
#define F_DIM 2048
#define E_NUM 8
#define RCAP 34816  // 2*T + 8*256 worst-case 256-padded rows

__device__ __forceinline__ unsigned short f2b(float f) {
  unsigned u = __float_as_uint(f);
  u += 0x7fff + ((u >> 16) & 1);
  return (unsigned short)(u >> 16);
}
__device__ __forceinline__ unsigned pk2(float a, float b) {
  __hip_bfloat162 h = __float22bfloat162_rn(make_float2(a, b));
  return *reinterpret_cast<unsigned*>(&h);
}

// ---------------- weight cast fp32 -> bf16 ----------------
__global__ void castw_k(const float* __restrict__ w1, const float* __restrict__ w2,
                        unsigned short* __restrict__ w1b, unsigned short* __restrict__ w2b) {
  size_t i = ((size_t)blockIdx.x * 256 + threadIdx.x) * 4;
  float4 a = *(const float4*)(w1 + i);
  float4 b = *(const float4*)(w2 + i);
  uint2 ua, ub;
  ua.x = pk2(a.x, a.y); ua.y = pk2(a.z, a.w);
  ub.x = pk2(b.x, b.y); ub.y = pk2(b.z, b.w);
  *(uint2*)(w1b + i) = ua;
  *(uint2*)(w2b + i) = ub;
}

// ---------------- router (+ fused x->bf16 cast) ----------------
__global__ void router_k(const float* __restrict__ x, const float* __restrict__ wr,
                         int* __restrict__ topi, float* __restrict__ topw,
                         float* __restrict__ probs8, unsigned short* __restrict__ xb) {
  int tid = threadIdx.x, wid = tid >> 6, lane = tid & 63;
  int t = blockIdx.x * 4 + wid;
  const float* xr = x + (size_t)t * D_DIM;
  float4 xv[4];
#pragma unroll
  for (int i = 0; i < 4; ++i) xv[i] = *(const float4*)(xr + i * 256 + lane * 4);
#pragma unroll
  for (int i = 0; i < 4; ++i) {
    uint2 u; u.x = pk2(xv[i].x, xv[i].y); u.y = pk2(xv[i].z, xv[i].w);
    *(uint2*)(xb + (size_t)t * D_DIM + i * 256 + lane * 4) = u;
  }
  float logit[E_NUM];
#pragma unroll
  for (int e = 0; e < E_NUM; ++e) {
    const float* wrow = wr + e * D_DIM;
    float p = 0.f;
#pragma unroll
    for (int i = 0; i < 4; ++i) {
      float4 wv = *(const float4*)(wrow + i * 256 + lane * 4);
      p += xv[i].x * wv.x + xv[i].y * wv.y + xv[i].z * wv.z + xv[i].w * wv.w;
    }
    for (int s = 32; s; s >>= 1) p += __shfl_xor(p, s);
    logit[e] = p;
  }
  if (lane == 0) {
    float m = logit[0];
    for (int e = 1; e < E_NUM; ++e) m = fmaxf(m, logit[e]);
    float pr[E_NUM];
    float sum = 0.f;
    for (int e = 0; e < E_NUM; ++e) { pr[e] = expf(logit[e] - m); sum += pr[e]; }
    float inv = 1.f / sum;
    for (int e = 0; e < E_NUM; ++e) { pr[e] *= inv; probs8[t * 8 + e] = pr[e]; }
    int i0 = 0;
    for (int e = 1; e < E_NUM; ++e) if (pr[e] > pr[i0]) i0 = e;
    int i1 = (i0 == 0) ? 1 : 0;
    for (int e = 0; e < E_NUM; ++e) if (e != i0 && pr[e] > pr[i1]) i1 = e;
    float wsum = pr[i0] + pr[i1];
    topi[2 * t] = i0;  topi[2 * t + 1] = i1;
    topw[2 * t] = pr[i0] / wsum;  topw[2 * t + 1] = pr[i1] / wsum;
  }
}

// ---------------- histogram ----------------
__global__ void hist_k(const int* __restrict__ topi, const float* __restrict__ probs8,
                       int* __restrict__ cnt, float* __restrict__ usage) {
  __shared__ int sc[E_NUM];
  __shared__ float su[E_NUM];
  int tid = threadIdx.x;
  if (tid < E_NUM) { sc[tid] = 0; su[tid] = 0.f; }
  __syncthreads();
  for (int i = blockIdx.x * 256 + tid; i < 2 * T_TOK; i += 256 * 64)
    atomicAdd(&sc[topi[i]], 1);
  for (int i = blockIdx.x * 256 + tid; i < 8 * T_TOK; i += 256 * 64)
    atomicAdd(&su[i & 7], probs8[i]);
  __syncthreads();
  if (tid < E_NUM) { atomicAdd(&cnt[tid], sc[tid]); atomicAdd(&usage[tid], su[tid]); }
}

// ---------------- offsets (256-padded) + aux ----------------
__global__ void scan_k(const int* __restrict__ cnt, int* __restrict__ offs,
                       const float* __restrict__ usage, float* __restrict__ aux) {
  if (threadIdx.x == 0 && blockIdx.x == 0) {
    int o = 0;
    for (int e = 0; e < E_NUM; ++e) { offs[e] = o; o += (cnt[e] + 255) & ~255; }
    offs[E_NUM] = o;
    float s = 0.f;
    for (int e = 0; e < E_NUM; ++e) { float m = usage[e] * (1.f / T_TOK); s += m * m; }
    *aux = (float)E_NUM * s;
  }
}

// ---------------- assignment: pair -> row ----------------
__global__ void assign_k(const int* __restrict__ topi, const int* __restrict__ offs,
                         int* __restrict__ cur, int* __restrict__ rowpair) {
  int p = blockIdx.x * 256 + threadIdx.x;
  int lane = threadIdx.x & 63;
  int e = topi[p];
  int r = 0;
#pragma unroll
  for (int ee = 0; ee < E_NUM; ++ee) {
    unsigned long long mask = __ballot(e == ee);
    if (e == ee) {
      int leader = __ffsll((unsigned long long)mask) - 1;
      int rank = __popcll(mask & ((1ull << lane) - 1ull));
      int b = 0;
      if (lane == leader) b = atomicAdd(&cur[ee], (int)__popcll(mask));
      b = __shfl(b, leader);
      r = offs[ee] + b + rank;
    }
  }
  rowpair[r] = p;
}

// ====== reg-staged (T14) GEMM body: 128x128 tile, BK=64, 4 waves, 32KB LDS ======
// Per K-step: [barrier]; ds_write regs(t); barrier; issue loads(t+1); ds_read+MFMA.
// LDS [128][64] shorts, XOR swizzle granule ^= (row&7) on write and read.
// Thread (j7=tid&7, rr=tid>>3) owns rows rr+{0,32,64,96}, granule j7:
// per load instr 8 consecutive lanes cover one row's full 128B line (coalesced).

#define RGEMM_BODY(NT, EPILOGUE)                                               \
  f32x4 acc[4][4] = {};                                                        \
  s16x8 rA[4], rB[4];                                                          \
  _Pragma("unroll") for (int i = 0; i < 4; ++i) {                              \
    rA[i] = *(const s16x8*)(pA[i]);                                            \
    rB[i] = *(const s16x8*)(pB[i]);                                            \
  }                                                                            \
  _Pragma("unroll 2")                                                          \
  for (int t = 0; t < NT; ++t) {                                               \
    if (t) __syncthreads();                                                    \
    _Pragma("unroll") for (int i = 0; i < 4; ++i) {                            \
      *(s16x8*)&As[wo[i]] = rA[i];                                             \
      *(s16x8*)&Bs[wo[i]] = rB[i];                                             \
    }                                                                          \
    __syncthreads();                                                           \
    if (t < NT - 1) {                                                          \
      int k0 = (t + 1) * 64;                                                   \
      _Pragma("unroll") for (int i = 0; i < 4; ++i) {                          \
        rA[i] = *(const s16x8*)(pA[i] + k0);                                   \
        rB[i] = *(const s16x8*)(pB[i] + k0);                                   \
      }                                                                        \
    }                                                                          \
    int ar = wm * 64 + rl, br = wn * 64 + rl;                                  \
    _Pragma("unroll") for (int kk = 0; kk < 2; ++kk) {                         \
      int cs = (((kk * 4 + g4) ^ (rl & 7)) << 3);                              \
      s16x8 a[4], b[4];                                                        \
      _Pragma("unroll") for (int m = 0; m < 4; ++m)                            \
        a[m] = *(const s16x8*)&As[(ar + m * 16) * 64 + cs];                    \
      _Pragma("unroll") for (int n = 0; n < 4; ++n)                            \
        b[n] = *(const s16x8*)&Bs[(br + n * 16) * 64 + cs];                    \
      __builtin_amdgcn_s_setprio(1);                                           \
      _Pragma("unroll") for (int m = 0; m < 4; ++m)                            \
        _Pragma("unroll") for (int n = 0; n < 4; ++n)                          \
          acc[m][n] = __builtin_amdgcn_mfma_f32_16x16x32_bf16(                 \
              a[m], b[n], acc[m][n], 0, 0, 0);                                 \
      __builtin_amdgcn_s_setprio(0);                                           \
    }                                                                          \
  }                                                                            \
  EPILOGUE

// ---------------- GEMM1: hseg = gelu(gather(xb) @ w1[e]^T) ----------------
__global__ __launch_bounds__(256, 3) void gemm1v_k(
    const unsigned short* __restrict__ xb, const unsigned short* __restrict__ w1b,
    const int* __restrict__ offs, const int* __restrict__ rowpair,
    const unsigned short* __restrict__ zrow,
    unsigned short* __restrict__ hseg, int segbase, int segrows) {
  int bid0 = blockIdx.x;
  int bid = ((bid0 & 7) << 11) | (bid0 >> 3);  // round-4 chunk swizzle (grid 16384)
  int e = bid >> 11, rem = bid & 2047, mt = rem >> 4, nt = rem & 15;
  int rend = offs[e + 1];
  int rowbase = offs[e] + mt * 128;
  if (rowbase >= rend || rowbase < segbase || rowbase >= segbase + segrows) return;

  __shared__ short As[128 * 64];
  __shared__ short Bs[128 * 64];
  int tid = threadIdx.x, wid = tid >> 6, lane = tid & 63;
  int wm = wid >> 1, wn = wid & 1, rl = lane & 15, g4 = lane >> 4;
  int j7 = tid & 7, rr = tid >> 3;  // rr 0..31
  int wg = ((j7 ^ (rr & 7)) << 3);
  int wo[4];
#pragma unroll
  for (int i = 0; i < 4; ++i) wo[i] = (rr + i * 32) * 64 + wg;

  const unsigned short* pA[4];
  const unsigned short* pB[4];
#pragma unroll
  for (int i = 0; i < 4; ++i) {
    int p = rowpair[rowbase + rr + i * 32];
    pA[i] = (p >= 0 ? xb + (size_t)(p >> 1) * D_DIM : zrow) + j7 * 8;
    pB[i] = w1b + ((size_t)e * F_DIM + nt * 128 + rr + i * 32) * D_DIM + j7 * 8;
  }

  RGEMM_BODY(16, {
    size_t rloc = (size_t)(rowbase - segbase);
    int c0 = nt * 128 + wn * 64 + rl;
    int lr0 = wm * 64 + (g4 << 2);
    _Pragma("unroll") for (int m = 0; m < 4; ++m)
      _Pragma("unroll") for (int j = 0; j < 4; ++j) {
        size_t rrow = (rloc + lr0 + m * 16 + j) * F_DIM;
        _Pragma("unroll") for (int n = 0; n < 4; ++n) {
          float v = acc[m][n][j];
          float g = 0.5f * v * (1.f + erff(v * 0.70710678118f));
          hseg[rrow + c0 + n * 16] = f2b(g);
        }
      }
  })
}

// ---------------- GEMM2: out[t] += w * (hseg @ w2[e]^T), atomic scatter ----------------
__global__ __launch_bounds__(256, 3) void gemm2v_k(
    const unsigned short* __restrict__ hseg, const unsigned short* __restrict__ w2b,
    const int* __restrict__ offs, const int* __restrict__ rowpair,
    const float* __restrict__ topw, float* __restrict__ out,
    int segbase, int segrows) {
  int bid0 = blockIdx.x;
  int bid = ((bid0 & 7) << 10) | (bid0 >> 3);  // round-4 chunk swizzle (grid 8192)
  int e = bid >> 10, rem = bid & 1023, mt = rem >> 3, nt = rem & 7;
  int rend = offs[e + 1];
  int rowbase = offs[e] + mt * 128;
  if (rowbase >= rend || rowbase < segbase || rowbase >= segbase + segrows) return;

  __shared__ short As[128 * 64];
  __shared__ short Bs[128 * 64];
  int tid = threadIdx.x, wid = tid >> 6, lane = tid & 63;
  int wm = wid >> 1, wn = wid & 1, rl = lane & 15, g4 = lane >> 4;
  int j7 = tid & 7, rr = tid >> 3;
  int wg = ((j7 ^ (rr & 7)) << 3);
  int wo[4];
#pragma unroll
  for (int i = 0; i < 4; ++i) wo[i] = (rr + i * 32) * 64 + wg;

  size_t rloc = (size_t)(rowbase - segbase);
  const unsigned short* pA[4];
  const unsigned short* pB[4];
#pragma unroll
  for (int i = 0; i < 4; ++i) {
    pA[i] = hseg + (rloc + rr + i * 32) * F_DIM + j7 * 8;
    pB[i] = w2b + ((size_t)e * D_DIM + nt * 128 + rr + i * 32) * F_DIM + j7 * 8;
  }

  RGEMM_BODY(32, {
    int c0 = nt * 128 + wn * 64 + rl;
    int lr0 = wm * 64 + (g4 << 2);
    _Pragma("unroll") for (int m = 0; m < 4; ++m)
      _Pragma("unroll") for (int j = 0; j < 4; ++j) {
        int lr = lr0 + m * 16 + j;
        int p = rowpair[rowbase + lr];
        if (p >= 0) {
          float wgt = topw[p];
          float* op = out + (size_t)(p >> 1) * D_DIM + c0;
          _Pragma("unroll") for (int n = 0; n < 4; ++n)
            unsafeAtomicAdd(op + n * 16, wgt * acc[m][n][j]);
        }
      }
  })
}

extern "C" void kernel_launch(void* const* d_in, const int* in_sizes, int n_in,
                              void* d_out, int out_size, void* d_ws, size_t ws_size,
                              hipStream_t stream) {
  const float* x  = (const float*)d_in[0];
  const float* wr = (const float*)d_in[1];
  const float* w1 = (const float*)d_in[2];
  const float* w2 = (const float*)d_in[3];
  float* out = (float*)d_out;

  char* ws = (char*)d_ws;
  int* cnt   = (int*)ws;               // [8]
  int* cur   = cnt + 8;                // [8]
  int* offs  = cnt + 16;               // [9]
  float* usage = (float*)(cnt + 25);   // [8]
  unsigned short* zrow = (unsigned short*)(ws + 4096);  // 2KB zeros (= D_DIM bf16)
  size_t off = 8192;
  int*   topi = (int*)(ws + off);     off += (size_t)2 * T_TOK * 4;
  float* topw = (float*)(ws + off);   off += (size_t)2 * T_TOK * 4;
  int*   rowpair = (int*)(ws + off);  off += (size_t)RCAP * 4;
  float* probs8 = (float*)(ws + off); off += (size_t)T_TOK * 8 * 4;
  off = (off + 255) & ~(size_t)255;

  unsigned short* xb = (unsigned short*)(ws + off);
  off += (size_t)T_TOK * D_DIM * 2;                       // 33.6 MB
  unsigned short* w1b = (unsigned short*)(ws + off);
  off += (size_t)E_NUM * F_DIM * D_DIM * 2;               // 33.6 MB
  unsigned short* w2b = (unsigned short*)(ws + off);
  off += (size_t)E_NUM * F_DIM * D_DIM * 2;               // 33.6 MB
  if (ws_size < off + (size_t)4096 * F_DIM * 2) return;   // need >= 16.8MB hseg
  size_t avail = ws_size - off;
  size_t segcap = (avail / ((size_t)F_DIM * 2)) & ~(size_t)255;
  int segrows = segcap > (size_t)RCAP ? RCAP : (int)segcap;
  unsigned short* hseg = (unsigned short*)(ws + off);
  int nseg = (RCAP + segrows - 1) / segrows;

  hipMemsetAsync(ws, 0, 8192, stream);
  hipMemsetAsync(rowpair, 0xFF, (size_t)RCAP * 4, stream);
  hipMemsetAsync(d_out, 0, (size_t)out_size * 4, stream);
  castw_k<<<16384, 256, 0, stream>>>(w1, w2, w1b, w2b);
  router_k<<<T_TOK / 4, 256, 0, stream>>>(x, wr, topi, topw, probs8, xb);
  hist_k<<<64, 256, 0, stream>>>(topi, probs8, cnt, usage);
  scan_k<<<1, 64, 0, stream>>>(cnt, offs, usage, out + (size_t)T_TOK * D_DIM);
  assign_k<<<2 * T_TOK / 256, 256, 0, stream>>>(topi, offs, cur, rowpair);

  for (int s = 0; s < nseg; ++s) {
    int segbase = s * segrows;
    gemm1v_k<<<16384, 256, 0, stream>>>(xb, w1b, offs, rowpair, zrow, hseg, segbase, segrows);
    gemm2v_k<<<8192, 256, 0, stream>>>(hseg, w2b, offs, rowpair, topw, out, segbase, segrows);
  }
}